// Round 5
// baseline (104.983 us; speedup 1.0000x reference)
//
#include <hip/hip_runtime.h>
#include <stdint.h>

// Problem constants (reference: B=8, N=16384, F=128, P=28)
#define FDIM  128
#define PDIM  28
#define MPTS  131072           // 8 * 16384 points
#define PSTR  4096             // f16 stride per p-slab: 4 fq * 2 kh * 32 f * 2 hi * 8 j

typedef _Float16 half8   __attribute__((ext_vector_type(8)));
typedef float    floatx16 __attribute__((ext_vector_type(16)));

// ---------------------------------------------------------------------------
// Prep: IF [F][P][P] fp32 -> IFt [28 p][4 fq][2 kh][32 fl][2 hi][8 j] f16.
// One (p, fq, kh) slab = 1024 B, contiguous & 1KB-aligned = EXACTLY one
// wave's B fragment for mfma_f32_32x32x16_f16:
//   B[k = hi*8 + j][n = fl] with k local = kh*16 + hi*8 + j (q), n = feature.
// q >= 28 zero-padded (kh=1,hi=1,j>=4).
// ---------------------------------------------------------------------------
__global__ __launch_bounds__(256) void prep_ift(const float* __restrict__ IF,
                                                _Float16* __restrict__ IFt) {
    int idx = blockIdx.x * 256 + threadIdx.x;     // 0 .. 28*4096-1
    int j   = idx & 7;
    int hi  = (idx >> 3) & 1;
    int fl  = (idx >> 4) & 31;
    int kh  = (idx >> 9) & 1;
    int fq  = (idx >> 10) & 3;
    int p   = idx >> 12;
    int q   = kh * 16 + hi * 8 + j;
    int f   = fq * 32 + fl;
    float v = (q < PDIM) ? IF[f * (PDIM * PDIM) + p * PDIM + q] : 0.0f;
    IFt[idx] = (_Float16)v;
}

// ---------------------------------------------------------------------------
// Main: C[m,f] = sum_{p,q} k0[m,p] * IF[f,p,q] * k1[m,q]
//
// ZERO LDS, ZERO BARRIERS. B (229 KB) is L2-resident; all 4 waves of a block
// read the same contiguous 1KB fragment slabs (L1-shared). Wave tile:
// 64 points (2 mt x 32) x 32 features, mfma_f32_32x32x16_f16, 28 p-steps,
// 2 k-halves per p, acc[2] of f32x16.
//  - k1 A-side: 32 expf/lane, hoisted to registers (p-invariant).
//  - k0: 2 expf per p, on the fly (TRANS pipe overlaps MFMA across waves).
//  - 16 free-running waves/CU: no sync points, compiler pipelines freely,
//    stores stream out under other waves' compute until kernel-end drain.
// ---------------------------------------------------------------------------
__global__ __launch_bounds__(256, 4) void feats_kernel(
    const float* __restrict__ x,       // [MPTS][2]
    const float* __restrict__ sigma,   // [1] log lengthscale
    const _Float16* __restrict__ IFt,  // [28][4][2][32][2][8] f16
    float* __restrict__ out)           // [MPTS][FDIM]
{
    const int tid   = threadIdx.x;
    const int lane  = tid & 63;
    const int wave  = tid >> 6;          // 0..3, stacked in m
    const int ln31  = lane & 31;
    const int hi    = lane >> 5;         // k-half-of-fragment select
    const int chunk = blockIdx.x >> 2;   // 256-point chunk (0..511)
    const int fq    = blockIdx.x & 3;    // feature quarter

    const int mbase = chunk * 256 + wave * 64;

    const float ls    = __expf(sigma[0]);
    const float inv   = 0.5f / (ls * ls);
    const float gstep = 0.998f / 27.0f;

    // ---- A-side k1 fragments (p-invariant) + x0, in registers ----
    // A layout (32x32x16): A[m = lane&31][k = hi*8 + j]; k local = q.
    // Fragment kh covers q = kh*16 + hi*8 + j. q>=28: finite garbage * B=0.
    half8 k1f[2][2];                     // [mt][kh]
    float x0v[2];
    #pragma unroll
    for (int mt = 0; mt < 2; mt++) {
        const int m = mbase + mt * 32 + ln31;
        const float2 xy = ((const float2*)x)[m];   // coalesced 8B
        x0v[mt] = xy.x;
        #pragma unroll
        for (int kh = 0; kh < 2; kh++)
            #pragma unroll
            for (int j = 0; j < 8; j++) {
                const float d = (0.001f + (kh * 16 + hi * 8 + j) * gstep) - xy.y;
                k1f[mt][kh][j] = (_Float16)__expf(-inv * d * d);
            }
    }

    floatx16 acc[2];
    #pragma unroll
    for (int mt = 0; mt < 2; mt++)
        #pragma unroll
        for (int r = 0; r < 16; r++)
            acc[mt][r] = 0.0f;

    // per-lane fragment base: fq*1024 + fl*16 + hi*8  (f16 units)
    const _Float16* gB = IFt + fq * 1024 + ln31 * 16 + hi * 8;

    // ---- K-loop: 2 contiguous-1KB global loads + 4 MFMA per p. ----
    #pragma unroll 4
    for (int p = 0; p < PDIM; p++) {
        const half8 bf0 = *(const half8*)(gB + p * PSTR);         // kh = 0
        const half8 bf1 = *(const half8*)(gB + p * PSTR + 512);   // kh = 1
        const float gp  = 0.001f + p * gstep;
        __builtin_amdgcn_s_setprio(1);
        #pragma unroll
        for (int mt = 0; mt < 2; mt++) {
            const float d  = gp - x0v[mt];
            const _Float16 k0 = (_Float16)__expf(-inv * d * d);
            acc[mt] = __builtin_amdgcn_mfma_f32_32x32x16_f16(
                k1f[mt][0] * k0, bf0, acc[mt], 0, 0, 0);
            acc[mt] = __builtin_amdgcn_mfma_f32_32x32x16_f16(
                k1f[mt][1] * k0, bf1, acc[mt], 0, 0, 0);
        }
        __builtin_amdgcn_s_setprio(0);
    }

    // ---- epilogue: C/D (32x32): col = lane&31, row = (r&3)+8*(r>>2)+4*hi.
    // Each store instr: 32 consecutive cols x 2 rows = two full 128B lines.
    const int col = fq * 32 + ln31;
    #pragma unroll
    for (int mt = 0; mt < 2; mt++) {
        const int row0 = mbase + mt * 32 + 4 * hi;
        #pragma unroll
        for (int r = 0; r < 16; r++) {
            const int row = row0 + (r & 3) + 8 * (r >> 2);
            __builtin_nontemporal_store(acc[mt][r],
                                        out + (size_t)row * FDIM + col);
        }
    }
}

// ---------------------------------------------------------------------------
extern "C" void kernel_launch(void* const* d_in, const int* in_sizes, int n_in,
                              void* d_out, int out_size, void* d_ws, size_t ws_size,
                              hipStream_t stream) {
    const float* x     = (const float*)d_in[0];   // [8,16384,2]
    const float* sigma = (const float*)d_in[1];   // [1]
    const float* IF    = (const float*)d_in[2];   // [128,28,28]
    float* out = (float*)d_out;                   // [8,16384,128] fp32

    // d_ws: IFt f16 [28][4096] = 229376 bytes
    _Float16* IFt = (_Float16*)d_ws;

    prep_ift<<<(PDIM * PSTR) / 256, 256, 0, stream>>>(IF, IFt);      // 448 blocks
    // 512 chunks of 256 points x 4 feature quarters = 2048 blocks of 4 waves.
    feats_kernel<<<(MPTS / 256) * 4, 256, 0, stream>>>(x, sigma, IFt, out);
}

// Round 6
// 103.068 us; speedup vs baseline: 1.0186x; 1.0186x over previous
//
#include <hip/hip_runtime.h>
#include <stdint.h>

// Problem constants (reference: B=8, N=16384, F=128, P=28)
#define FDIM  128
#define PDIM  28
#define MPTS  131072           // 8 * 16384 points
#define PSTR  4096             // f16 stride per p-slab: 4 fq * 2 kh * 32 f * 2 hi * 8 j

typedef _Float16 half8   __attribute__((ext_vector_type(8)));
typedef _Float16 half2v  __attribute__((ext_vector_type(2)));
typedef float    floatx16 __attribute__((ext_vector_type(16)));

// ---------------------------------------------------------------------------
// Prep: IF [F][P][P] fp32 -> IFt [28 p][4 fq][2 kh][32 fl][2 hi][8 j] f16.
// One (p, fq, kh) slab = 1024 B, contiguous & 1KB-aligned = EXACTLY one
// wave's B fragment for mfma_f32_32x32x16_f16:
//   B[k = hi*8 + j][n = fl] with k local = kh*16 + hi*8 + j (q), n = feature.
// q >= 28 zero-padded (kh=1,hi=1,j>=4).
// ---------------------------------------------------------------------------
__global__ __launch_bounds__(256) void prep_ift(const float* __restrict__ IF,
                                                _Float16* __restrict__ IFt) {
    int idx = blockIdx.x * 256 + threadIdx.x;     // 0 .. 28*4096-1
    int j   = idx & 7;
    int hi  = (idx >> 3) & 1;
    int fl  = (idx >> 4) & 31;
    int kh  = (idx >> 9) & 1;
    int fq  = (idx >> 10) & 3;
    int p   = idx >> 12;
    int q   = kh * 16 + hi * 8 + j;
    int f   = fq * 32 + fl;
    float v = (q < PDIM) ? IF[f * (PDIM * PDIM) + p * PDIM + q] : 0.0f;
    IFt[idx] = (_Float16)v;
}

// ---------------------------------------------------------------------------
// Main: C[m,f] = sum_{p,q} k0[m,p] * IF[f,p,q] * k1[m,q]
//
// ZERO LDS, ZERO BARRIERS, and a K-loop critical path stripped to
// {prefetched load -> pk_mul -> MFMA}:
//  - ALL k0 values (28 p x 2 mt) hoisted to 28 packed half2 registers in the
//    prologue: no TRANS/cvt/pack in the loop body.
//  - B fragments: explicit 2-deep software prefetch in named registers
//    (static rotation, compile-time tail guards) so every load has ~2 full
//    iteration bodies + cross-wave overlap to cover L2 latency.
//  - no s_setprio / no builtins in the body: nothing blocks the scheduler
//    from hoisting and interleaving across iterations.
// Wave tile: 64 points (2 mt x 32) x 32 features, mfma_f32_32x32x16_f16,
// 28 p-steps, acc[2] of f32x16. ~108 VGPR -> 4 waves/SIMD.
// ---------------------------------------------------------------------------
__global__ __launch_bounds__(256, 4) void feats_kernel(
    const float* __restrict__ x,       // [MPTS][2]
    const float* __restrict__ sigma,   // [1] log lengthscale
    const _Float16* __restrict__ IFt,  // [28][4][2][32][2][8] f16
    float* __restrict__ out)           // [MPTS][FDIM]
{
    const int tid   = threadIdx.x;
    const int lane  = tid & 63;
    const int wave  = tid >> 6;          // 0..3, stacked in m
    const int ln31  = lane & 31;
    const int hi    = lane >> 5;         // k-half-of-fragment select
    const int chunk = blockIdx.x >> 2;   // 256-point chunk (0..511)
    const int fq    = blockIdx.x & 3;    // feature quarter

    const int mbase = chunk * 256 + wave * 64;

    const float ls    = __expf(sigma[0]);
    const float inv   = 0.5f / (ls * ls);
    const float gstep = 0.998f / 27.0f;

    // per-lane fragment base: fq*1024 + fl*16 + hi*8  (f16 units)
    const _Float16* gB = IFt + fq * 1024 + ln31 * 16 + hi * 8;

    // ---- issue first two p-slabs' loads IMMEDIATELY (deepest latency cover)
    half8 bA0 = *(const half8*)(gB + 0 * PSTR);
    half8 bA1 = *(const half8*)(gB + 0 * PSTR + 512);
    half8 bB0 = *(const half8*)(gB + 1 * PSTR);
    half8 bB1 = *(const half8*)(gB + 1 * PSTR + 512);

    // ---- A-side k1 fragments (p-invariant) + x0, in registers ----
    // A layout (32x32x16): A[m = lane&31][k = hi*8 + j]; k local = q.
    // Fragment kh covers q = kh*16 + hi*8 + j. q>=28: finite garbage * B=0.
    half8 k1f[2][2];                     // [mt][kh]
    float x0v[2];
    #pragma unroll
    for (int mt = 0; mt < 2; mt++) {
        const int m = mbase + mt * 32 + ln31;
        const float2 xy = ((const float2*)x)[m];   // coalesced 8B
        x0v[mt] = xy.x;
        #pragma unroll
        for (int kh = 0; kh < 2; kh++)
            #pragma unroll
            for (int j = 0; j < 8; j++) {
                const float d = (0.001f + (kh * 16 + hi * 8 + j) * gstep) - xy.y;
                k1f[mt][kh][j] = (_Float16)__expf(-inv * d * d);
            }
    }

    // ---- hoist ALL k0: 28 packed half2 (mt0 in lane .x, mt1 in .y) ----
    half2v k0h[PDIM];
    #pragma unroll
    for (int p = 0; p < PDIM; p++) {
        const float gp = 0.001f + p * gstep;
        const float d0 = gp - x0v[0];
        const float d1 = gp - x0v[1];
        k0h[p][0] = (_Float16)__expf(-inv * d0 * d0);
        k0h[p][1] = (_Float16)__expf(-inv * d1 * d1);
    }

    floatx16 acc[2];
    #pragma unroll
    for (int mt = 0; mt < 2; mt++)
        #pragma unroll
        for (int r = 0; r < 16; r++)
            acc[mt][r] = 0.0f;

    // ---- K-loop: fully unrolled pairs, 2-deep static prefetch rotation ----
    #pragma unroll
    for (int pp = 0; pp < PDIM; pp += 2) {
        {   // p = pp : consume bA, prefetch pp+2
            const half8 f0 = bA0, f1 = bA1;
            if (pp + 2 < PDIM) {
                bA0 = *(const half8*)(gB + (pp + 2) * PSTR);
                bA1 = *(const half8*)(gB + (pp + 2) * PSTR + 512);
            }
            #pragma unroll
            for (int mt = 0; mt < 2; mt++) {
                const _Float16 k0 = k0h[pp][mt];
                acc[mt] = __builtin_amdgcn_mfma_f32_32x32x16_f16(
                    k1f[mt][0] * k0, f0, acc[mt], 0, 0, 0);
                acc[mt] = __builtin_amdgcn_mfma_f32_32x32x16_f16(
                    k1f[mt][1] * k0, f1, acc[mt], 0, 0, 0);
            }
        }
        {   // p = pp+1 : consume bB, prefetch pp+3
            const half8 f0 = bB0, f1 = bB1;
            if (pp + 3 < PDIM) {
                bB0 = *(const half8*)(gB + (pp + 3) * PSTR);
                bB1 = *(const half8*)(gB + (pp + 3) * PSTR + 512);
            }
            #pragma unroll
            for (int mt = 0; mt < 2; mt++) {
                const _Float16 k0 = k0h[pp + 1][mt];
                acc[mt] = __builtin_amdgcn_mfma_f32_32x32x16_f16(
                    k1f[mt][0] * k0, f0, acc[mt], 0, 0, 0);
                acc[mt] = __builtin_amdgcn_mfma_f32_32x32x16_f16(
                    k1f[mt][1] * k0, f1, acc[mt], 0, 0, 0);
            }
        }
    }

    // ---- epilogue: C/D (32x32): col = lane&31, row = (r&3)+8*(r>>2)+4*hi.
    // Each store: 32 consecutive cols x 4B = full 128B lines.
    const int col = fq * 32 + ln31;
    #pragma unroll
    for (int mt = 0; mt < 2; mt++) {
        const int row0 = mbase + mt * 32 + 4 * hi;
        #pragma unroll
        for (int r = 0; r < 16; r++) {
            const int row = row0 + (r & 3) + 8 * (r >> 2);
            __builtin_nontemporal_store(acc[mt][r],
                                        out + (size_t)row * FDIM + col);
        }
    }
}

// ---------------------------------------------------------------------------
extern "C" void kernel_launch(void* const* d_in, const int* in_sizes, int n_in,
                              void* d_out, int out_size, void* d_ws, size_t ws_size,
                              hipStream_t stream) {
    const float* x     = (const float*)d_in[0];   // [8,16384,2]
    const float* sigma = (const float*)d_in[1];   // [1]
    const float* IF    = (const float*)d_in[2];   // [128,28,28]
    float* out = (float*)d_out;                   // [8,16384,128] fp32

    // d_ws: IFt f16 [28][4096] = 229376 bytes
    _Float16* IFt = (_Float16*)d_ws;

    prep_ift<<<(PDIM * PSTR) / 256, 256, 0, stream>>>(IF, IFt);      // 448 blocks
    // 512 chunks of 256 points x 4 feature quarters = 2048 blocks of 4 waves.
    feats_kernel<<<(MPTS / 256) * 4, 256, 0, stream>>>(x, sigma, IFt, out);
}

// Round 7
// 100.770 us; speedup vs baseline: 1.0418x; 1.0228x over previous
//
#include <hip/hip_runtime.h>
#include <stdint.h>

// Problem constants (reference: B=8, N=16384, F=128, P=28)
#define FDIM  128
#define PDIM  28
#define MPTS  131072           // 8 * 16384 points
#define PSTR  4096             // f16 stride per p-slab: 4 fq * 2 kh * 32 f * 2 hi * 8 j

typedef _Float16 half8   __attribute__((ext_vector_type(8)));
typedef float    floatx16 __attribute__((ext_vector_type(16)));

// ---------------------------------------------------------------------------
// Prep: IF [F][P][P] fp32 -> IFt [28 p][4 fq][2 kh][32 fl][2 hi][8 j] f16.
// One (p, fq, kh) slab = 1024 B, contiguous & 1KB-aligned = EXACTLY one
// wave's B fragment for mfma_f32_32x32x16_f16:
//   B[k = hi*8 + j][n = fl] with k local = kh*16 + hi*8 + j (q), n = feature.
// q >= 28 zero-padded (kh=1,hi=1,j>=4).
// ---------------------------------------------------------------------------
__global__ __launch_bounds__(256) void prep_ift(const float* __restrict__ IF,
                                                _Float16* __restrict__ IFt) {
    int idx = blockIdx.x * 256 + threadIdx.x;     // 0 .. 28*4096-1
    int j   = idx & 7;
    int hi  = (idx >> 3) & 1;
    int fl  = (idx >> 4) & 31;
    int kh  = (idx >> 9) & 1;
    int fq  = (idx >> 10) & 3;
    int p   = idx >> 12;
    int q   = kh * 16 + hi * 8 + j;
    int f   = fq * 32 + fl;
    float v = (q < PDIM) ? IF[f * (PDIM * PDIM) + p * PDIM + q] : 0.0f;
    IFt[idx] = (_Float16)v;
}

// ---------------------------------------------------------------------------
// Main: C[m,f] = sum_{p,q} k0[m,p] * IF[f,p,q] * k1[m,q]
//
// ZERO LDS, ZERO BARRIERS; the change vs last round is OPERAND TRAFFIC PER
// FLOP: wave tile is now 128 points x 32 features (mt=4), so each 2KB B-slab
// load feeds 8 MFMAs instead of 4 — per-CU L1/TA time halves (the pipe that
// was co-saturated with MFMA), and total wave count halves.
//  - k1 A-fragments hoisted (p-invariant, 64 expf/lane amortized over 2x
//    output); k0 computed in-loop (4 expf per p on the TRANS pipe, hidden
//    under ~256 cyc of MFMA per p).
//  - B fragments: 2-deep static prefetch rotation (named regs, rule-20 safe).
//  - 4 same-fq waves per block -> all share the same B slabs in L1.
// acc[4] f32x16 + k1f 32 + prefetch 16 => ~130 VGPR -> 3 waves/SIMD.
// ---------------------------------------------------------------------------
__global__ __launch_bounds__(256, 3) void feats_kernel(
    const float* __restrict__ x,       // [MPTS][2]
    const float* __restrict__ sigma,   // [1] log lengthscale
    const _Float16* __restrict__ IFt,  // [28][4][2][32][2][8] f16
    float* __restrict__ out)           // [MPTS][FDIM]
{
    const int tid   = threadIdx.x;
    const int lane  = tid & 63;
    const int wave  = tid >> 6;          // 0..3, stacked in m
    const int ln31  = lane & 31;
    const int hi    = lane >> 5;         // k-half-of-fragment select
    const int chunk = blockIdx.x >> 2;   // 512-point chunk (0..255)
    const int fq    = blockIdx.x & 3;    // feature quarter

    const int mbase = chunk * 512 + wave * 128;

    const float ls    = __expf(sigma[0]);
    const float inv   = 0.5f / (ls * ls);
    const float gstep = 0.998f / 27.0f;

    // per-lane fragment base: fq*1024 + fl*16 + hi*8  (f16 units)
    const _Float16* gB = IFt + fq * 1024 + ln31 * 16 + hi * 8;

    // ---- issue first two p-slabs' loads IMMEDIATELY (deepest latency cover)
    half8 bA0 = *(const half8*)(gB + 0 * PSTR);
    half8 bA1 = *(const half8*)(gB + 0 * PSTR + 512);
    half8 bB0 = *(const half8*)(gB + 1 * PSTR);
    half8 bB1 = *(const half8*)(gB + 1 * PSTR + 512);

    // ---- A-side k1 fragments (p-invariant) + x0, in registers ----
    // A layout (32x32x16): A[m = lane&31][k = hi*8 + j]; k local = q.
    // Fragment kh covers q = kh*16 + hi*8 + j. q>=28: finite garbage * B=0.
    half8 k1f[4][2];                     // [mt][kh]
    float x0v[4];
    #pragma unroll
    for (int mt = 0; mt < 4; mt++) {
        const int m = mbase + mt * 32 + ln31;
        const float2 xy = ((const float2*)x)[m];   // coalesced 8B
        x0v[mt] = xy.x;
        #pragma unroll
        for (int kh = 0; kh < 2; kh++)
            #pragma unroll
            for (int j = 0; j < 8; j++) {
                const float d = (0.001f + (kh * 16 + hi * 8 + j) * gstep) - xy.y;
                k1f[mt][kh][j] = (_Float16)__expf(-inv * d * d);
            }
    }

    floatx16 acc[4];
    #pragma unroll
    for (int mt = 0; mt < 4; mt++)
        #pragma unroll
        for (int r = 0; r < 16; r++)
            acc[mt][r] = 0.0f;

    // ---- K-loop: fully unrolled pairs, 2-deep static prefetch rotation.
    // Per p: 2 loads (2KB) -> 8 MFMA; 4 expf (TRANS) + 32 pk_mul (VALU)
    // hide under ~256 cyc of MFMA issue. ----
    #pragma unroll
    for (int pp = 0; pp < PDIM; pp += 2) {
        {   // p = pp : consume bA, prefetch pp+2
            const half8 f0 = bA0, f1 = bA1;
            if (pp + 2 < PDIM) {
                bA0 = *(const half8*)(gB + (pp + 2) * PSTR);
                bA1 = *(const half8*)(gB + (pp + 2) * PSTR + 512);
            }
            const float gp = 0.001f + pp * gstep;
            #pragma unroll
            for (int mt = 0; mt < 4; mt++) {
                const float d = gp - x0v[mt];
                const _Float16 k0 = (_Float16)__expf(-inv * d * d);
                acc[mt] = __builtin_amdgcn_mfma_f32_32x32x16_f16(
                    k1f[mt][0] * k0, f0, acc[mt], 0, 0, 0);
                acc[mt] = __builtin_amdgcn_mfma_f32_32x32x16_f16(
                    k1f[mt][1] * k0, f1, acc[mt], 0, 0, 0);
            }
        }
        {   // p = pp+1 : consume bB, prefetch pp+3
            const half8 f0 = bB0, f1 = bB1;
            if (pp + 3 < PDIM) {
                bB0 = *(const half8*)(gB + (pp + 3) * PSTR);
                bB1 = *(const half8*)(gB + (pp + 3) * PSTR + 512);
            }
            const float gp = 0.001f + (pp + 1) * gstep;
            #pragma unroll
            for (int mt = 0; mt < 4; mt++) {
                const float d = gp - x0v[mt];
                const _Float16 k0 = (_Float16)__expf(-inv * d * d);
                acc[mt] = __builtin_amdgcn_mfma_f32_32x32x16_f16(
                    k1f[mt][0] * k0, f0, acc[mt], 0, 0, 0);
                acc[mt] = __builtin_amdgcn_mfma_f32_32x32x16_f16(
                    k1f[mt][1] * k0, f1, acc[mt], 0, 0, 0);
            }
        }
    }

    // ---- epilogue: C/D (32x32): col = lane&31, row = (r&3)+8*(r>>2)+4*hi.
    // Each store: 32 consecutive cols x 4B = a full 128B line. ----
    const int col = fq * 32 + ln31;
    #pragma unroll
    for (int mt = 0; mt < 4; mt++) {
        const int row0 = mbase + mt * 32 + 4 * hi;
        #pragma unroll
        for (int r = 0; r < 16; r++) {
            const int row = row0 + (r & 3) + 8 * (r >> 2);
            __builtin_nontemporal_store(acc[mt][r],
                                        out + (size_t)row * FDIM + col);
        }
    }
}

// ---------------------------------------------------------------------------
extern "C" void kernel_launch(void* const* d_in, const int* in_sizes, int n_in,
                              void* d_out, int out_size, void* d_ws, size_t ws_size,
                              hipStream_t stream) {
    const float* x     = (const float*)d_in[0];   // [8,16384,2]
    const float* sigma = (const float*)d_in[1];   // [1]
    const float* IF    = (const float*)d_in[2];   // [128,28,28]
    float* out = (float*)d_out;                   // [8,16384,128] fp32

    // d_ws: IFt f16 [28][4096] = 229376 bytes
    _Float16* IFt = (_Float16*)d_ws;

    prep_ift<<<(PDIM * PSTR) / 256, 256, 0, stream>>>(IF, IFt);      // 448 blocks
    // 256 chunks of 512 points x 4 feature quarters = 1024 blocks of 4 waves,
    // all 4 waves of a block share one fq -> B slabs shared in L1.
    feats_kernel<<<(MPTS / 512) * 4, 256, 0, stream>>>(x, sigma, IFt, out);
}